// Round 21
// baseline (177.479 us; speedup 1.0000x reference)
//
#include <hip/hip_runtime.h>
#include <hip/hip_fp16.h>

typedef _Float16 f16;
typedef _Float16 half4 __attribute__((ext_vector_type(4)));
typedef _Float16 half8 __attribute__((ext_vector_type(8)));
typedef float f32x4 __attribute__((ext_vector_type(4)));

#define BATCH 8
#define NTOK 2048
#define FIN 256
#define FOUT 256
#define ALPHA 0.2f
#define LOG2E 1.44269504088896340736f

// WhT swizzled layout: [b][slab(32)][o(256)][u(8)][q(8)] f16; logical
// Wh[n][o] (n = slab*64 + jg8*8 + jq) lives at u = jg8 ^ (o & 7).
// Each slab is a contiguous 32 KB block == its LDS image in k_attn.

// ---------------- K0: W[k][o] fp32 -> WT[o][k] fp16 ----------------
__global__ void k_wt(const float* __restrict__ W, f16* __restrict__ WT) {
    __shared__ float t[32][33];
    int o0 = blockIdx.x * 32, k0 = blockIdx.y * 32;
    int tx = threadIdx.x, ty = threadIdx.y;
    t[ty][tx] = W[(k0 + ty) * FOUT + o0 + tx];
    __syncthreads();
    WT[(o0 + ty) * FIN + (k0 + tx)] = (f16)t[tx][ty];
}

// ---------------- K1: gemm -> swizzled WhT slab + fused s1/s2 epilogue ----------------
__global__ __launch_bounds__(256) void k_gemm(const float* __restrict__ x,
                                              const f16* __restrict__ WT,
                                              const float* __restrict__ a,
                                              f16* __restrict__ WhT,
                                              float* __restrict__ s1,
                                              float* __restrict__ s2) {
    __shared__ __align__(16) char gsmem[46080];
    int t = threadIdx.x;
    int lane = t & 63, w = t >> 6;
    f16* Ah = (f16*)gsmem;               // [64][72]
    f16* Bt = (f16*)(gsmem + 9216);      // [256][72]
    int m0 = blockIdx.x * 64;
    int lr = lane & 15, lg = lane >> 4;
    f32x4 acc[4][4] = {};

    for (int k0 = 0; k0 < FIN; k0 += 64) {
        {
            int r = t >> 2, c = (t & 3) * 16;
            const float* src = x + (size_t)(m0 + r) * FIN + k0 + c;
            f32x4 v0 = *(const f32x4*)(src);
            f32x4 v1 = *(const f32x4*)(src + 4);
            f32x4 v2 = *(const f32x4*)(src + 8);
            f32x4 v3 = *(const f32x4*)(src + 12);
            half8 h0, h1;
#pragma unroll
            for (int q = 0; q < 4; q++) {
                h0[q] = (f16)v0[q]; h0[q + 4] = (f16)v1[q];
                h1[q] = (f16)v2[q]; h1[q + 4] = (f16)v3[q];
            }
            f16* dst = Ah + r * 72 + c;
            *(half8*)dst = h0;
            *(half8*)(dst + 8) = h1;
        }
        {
            const f16* src = WT + (size_t)t * FIN + k0;
            f16* dst = Bt + t * 72;
#pragma unroll
            for (int q = 0; q < 8; q++)
                *(half8*)(dst + q * 8) = *(const half8*)(src + q * 8);
        }
        __syncthreads();
#pragma unroll
        for (int kc = 0; kc < 2; kc++) {
            int krow = kc * 32 + lg * 8;
            half8 af[4], bf[4];
#pragma unroll
            for (int fi = 0; fi < 4; fi++)
                af[fi] = *(half8*)(Ah + (fi * 16 + lr) * 72 + krow);
#pragma unroll
            for (int fo = 0; fo < 4; fo++)
                bf[fo] = *(half8*)(Bt + (w * 64 + fo * 16 + lr) * 72 + krow);
#pragma unroll
            for (int fi = 0; fi < 4; fi++)
#pragma unroll
                for (int fo = 0; fo < 4; fo++)
                    acc[fi][fo] = __builtin_amdgcn_mfma_f32_16x16x32_f16(
                        af[fi], bf[fo], acc[fi][fo], 0, 0, 0);
        }
        __syncthreads();
    }

    int b = m0 >> 11;
    int slab_i = (m0 & (NTOK - 1)) >> 6;
    int nbase = m0 & (NTOK - 1);

    float* sred = (float*)gsmem;          // aliases Ah
    f16* slab = (f16*)(gsmem + 9216);     // 32 KB slab image (aliases Bt)
    float a1v[4], a2v[4];
#pragma unroll
    for (int fo = 0; fo < 4; fo++) {
        int o = w * 64 + fo * 16 + lr;
        a1v[fo] = a[o];
        a2v[fo] = a[FOUT + o];
    }
#pragma unroll
    for (int fi = 0; fi < 4; fi++) {
        f32x4 p1 = {}, p2 = {};
#pragma unroll
        for (int fo = 0; fo < 4; fo++) {
            p1 += acc[fi][fo] * a1v[fo];
            p2 += acc[fi][fo] * a2v[fo];
        }
#pragma unroll
        for (int q = 0; q < 4; q++) {
#pragma unroll
            for (int d = 1; d < 16; d <<= 1) {
                p1[q] += __shfl_xor(p1[q], d);
                p2[q] += __shfl_xor(p2[q], d);
            }
        }
        if (lr == 0) {
            int row = fi * 16 + lg * 4;
#pragma unroll
            for (int q = 0; q < 4; q++) {
                sred[w * 64 + row + q] = p1[q];
                sred[256 + w * 64 + row + q] = p2[q];
            }
        }
    }
#pragma unroll
    for (int fi = 0; fi < 4; fi++) {
        int jg8 = fi * 2 + (lg >> 1), jq0 = (lg & 1) * 4;
#pragma unroll
        for (int fo = 0; fo < 4; fo++) {
            int o = w * 64 + fo * 16 + lr;
            half4 hv;
#pragma unroll
            for (int q = 0; q < 4; q++) hv[q] = (f16)acc[fi][fo][q];
            *(half4*)(slab + o * 64 + ((jg8 ^ (o & 7)) * 8) + jq0) = hv;
        }
    }
    __syncthreads();

    if (t < 64) {
        s1[(size_t)b * NTOK + nbase + t] =
            sred[t] + sred[64 + t] + sred[128 + t] + sred[192 + t];
    } else if (t < 128) {
        int r2 = t - 64;
        s2[(size_t)b * NTOK + nbase + r2] =
            sred[256 + r2] + sred[320 + r2] + sred[384 + r2] + sred[448 + r2];
    }
    {
        const int4* sl = (const int4*)slab;
        int4* gd = (int4*)(WhT + ((size_t)(b * 32 + slab_i) * 256) * 64);
#pragma unroll
        for (int i = 0; i < 8; i++) gd[i * 256 + t] = sl[i * 256 + t];
    }
}

// ---------------- K3: self-packing fused attn, 32-row blocks, 2 blocks/CU ----------------
// Grid 512 (= 2 blocks/CU exactly). Slab reg-staged (global->reg a step early,
// ds_write after bar2) -> single 32 KB Bl with bulletproof barrier ordering.
// Single P (4 KB). LDS total ~52.4 KB. Numerics identical to R19 (passed).
__global__ __launch_bounds__(512, 4) void k_attn(const int* __restrict__ adj,
                                                 const f16* __restrict__ WhT,
                                                 const float* __restrict__ s1g,
                                                 const float* __restrict__ s2g,
                                                 float* __restrict__ out) {
    __shared__ __align__(16) char smem[53664];
    f16* Bl = (f16*)smem;                               // 32 KB slab (single)
    float* s2_lds = (float*)(smem + 32768);             // [2048] (scaled)
    unsigned* mask_lds = (unsigned*)(smem + 40960);     // [32][66] u32
    char* P_b = smem + 49408;                           // [32][64] f16 = 4 KB
    float* l_lds = (float*)(smem + 53504);              // [32]
    float* wmax = (float*)(smem + 53632);               // [8]

    int b = blockIdx.x & 7;                             // batch -> XCD pinning
    int i0 = (blockIdx.x >> 3) * 32;
    int t = threadIdx.x;
    int lane = t & 63, w = t >> 6;
    int lr = lane & 15, lg = lane >> 4;
    int r4 = lane >> 4, jg = lane & 15;
    int srow = w * 4 + r4;                              // softmax-role row [0,32)

    {   // s2 -> LDS (scaled by log2e) + block max
        f32x4 sv4 = ((const f32x4*)(s2g + (size_t)b * NTOK))[t];
        sv4 = sv4 * LOG2E;
        ((f32x4*)s2_lds)[t] = sv4;
        float tmx = fmaxf(fmaxf(sv4[0], sv4[1]), fmaxf(sv4[2], sv4[3]));
#pragma unroll
        for (int d = 1; d < 64; d <<= 1) tmx = fmaxf(tmx, __shfl_xor(tmx, d));
        if (lane == 0) wmax[w] = tmx;
    }

    const char* wsrc = (const char*)WhT + (size_t)b * (32 * 32768);
    int4 st[4];
    {   // slab 0 -> regs
        const int4* p = (const int4*)(wsrc + t * 16);
        st[0] = p[0]; st[1] = p[512]; st[2] = p[1024]; st[3] = p[1536];
    }

    {   // adj self-pack: wave w -> rows w*4..+4, row-contiguous, 1-row prefetch
        const int4* abase = (const int4*)(adj + ((size_t)(b * NTOK + i0 + w * 4)) * NTOK)
                            + lane * 8;
        int4 cur[8], nxt[8];
#pragma unroll
        for (int k = 0; k < 8; k++) cur[k] = abase[k];
        for (int r = 0; r < 4; r++) {
            if (r < 3) {
#pragma unroll
                for (int k = 0; k < 8; k++) nxt[k] = abase[(r + 1) * 512 + k];
            } else {
#pragma unroll
                for (int k = 0; k < 8; k++) nxt[k] = cur[k];
            }
            unsigned m = 0;
#pragma unroll
            for (int k = 0; k < 8; k++) {
                m |= (unsigned)(cur[k].x > 0) << (k * 4);
                m |= (unsigned)(cur[k].y > 0) << (k * 4 + 1);
                m |= (unsigned)(cur[k].z > 0) << (k * 4 + 2);
                m |= (unsigned)(cur[k].w > 0) << (k * 4 + 3);
            }
            mask_lds[(w * 4 + r) * 66 + lane] = m;
#pragma unroll
            for (int k = 0; k < 8; k++) cur[k] = nxt[k];
        }
    }

    {   // slab0 regs -> LDS; issue slab1 -> regs
        int4* q = (int4*)(smem + t * 16);
        q[0] = st[0]; q[512] = st[1]; q[1024] = st[2]; q[1536] = st[3];
        const int4* p = (const int4*)(wsrc + 32768 + t * 16);
        st[0] = p[0]; st[1] = p[512]; st[2] = p[1024]; st[3] = p[1536];
    }

    float s1r = s1g[(size_t)b * NTOK + i0 + srow] * LOG2E;
    float l_acc = 0.f;

    __syncthreads();                                    // s2+wmax+mask+slab0 ready

    float s2m = wmax[0];
#pragma unroll
    for (int k = 1; k < 8; k++) s2m = fmaxf(s2m, wmax[k]);
    float txr = s1r + s2m;
    float mxr = fmaxf(txr, ALPHA * txr);                // fixed shift (scaled)

    f32x4 acc[2][2] = {};                               // [fi][ot], o-range w*32..+32

    for (int s = 0; s < 32; s++) {
        {   // phase A: softmax (each lane: 4 elements of its row)
            unsigned word = mask_lds[srow * 66 + s * 2 + (jg >> 3)];
            unsigned bits = (word >> ((jg & 7) * 4)) & 0xfu;
            f32x4 sA = *(const f32x4*)&s2_lds[s * 64 + jg * 4];
            half4 ph;
#pragma unroll
            for (int q = 0; q < 4; q++) {
                float sx = s1r + sA[q];
                float ev = fmaxf(sx, ALPHA * sx);
                float p = ((bits >> q) & 1) ? exp2f(ev - mxr) : 0.f;
                l_acc += p;
                ph[q] = (f16)p;
            }
            *(half4*)(P_b + srow * 128 + (((jg >> 1) ^ (srow & 7)) * 16) + (jg & 1) * 8) = ph;
        }
        __syncthreads();                                // P(s) + (prev ds_writes) ready

        {   // phase B: MFMA (wave: both row-tiles x 32 o-cols)
            half8 af[2][2];
#pragma unroll
            for (int fi = 0; fi < 2; fi++)
#pragma unroll
                for (int kc = 0; kc < 2; kc++) {
                    int ra = fi * 16 + lr;
                    af[fi][kc] = *(const half8*)(P_b + ra * 128 + (((kc * 4 + lg) ^ (ra & 7)) * 16));
                }
#pragma unroll
            for (int ot = 0; ot < 2; ot++) {
                int o = w * 32 + ot * 16 + lr;
#pragma unroll
                for (int kc = 0; kc < 2; kc++) {
                    half8 bf = *(const half8*)((char*)Bl + o * 128 + (((kc * 4 + lg) ^ (o & 7)) * 16));
                    acc[0][ot] = __builtin_amdgcn_mfma_f32_16x16x32_f16(af[0][kc], bf, acc[0][ot], 0, 0, 0);
                    acc[1][ot] = __builtin_amdgcn_mfma_f32_16x16x32_f16(af[1][kc], bf, acc[1][ot], 0, 0, 0);
                }
            }
        }
        __syncthreads();                                // Bl/P reads complete

        if (s < 31) {                                   // regs -> Bl (slab s+1)
            int4* q = (int4*)(smem + t * 16);
            q[0] = st[0]; q[512] = st[1]; q[1024] = st[2]; q[1536] = st[3];
            if (s < 30) {                               // issue slab s+2 -> regs
                const int4* p = (const int4*)(wsrc + (size_t)(s + 2) * 32768 + t * 16);
                st[0] = p[0]; st[1] = p[512]; st[2] = p[1024]; st[3] = p[1536];
            }
        }
    }

    // l: reduce over the 16 jg-lanes of each row
    l_acc += __shfl_xor(l_acc, 1);
    l_acc += __shfl_xor(l_acc, 2);
    l_acc += __shfl_xor(l_acc, 4);
    l_acc += __shfl_xor(l_acc, 8);
    if (jg == 0) l_lds[srow] = l_acc;
    __syncthreads();

    // epilogue: divide + ELU + store (wave owns all 32 rows x its 32 o-cols)
    f32x4 rl0, rl1;
#pragma unroll
    for (int q = 0; q < 4; q++) {
        rl0[q] = 1.f / l_lds[lg * 4 + q];
        rl1[q] = 1.f / l_lds[16 + lg * 4 + q];
    }
#pragma unroll
    for (int ot = 0; ot < 2; ot++) {
        int o = w * 32 + ot * 16 + lr;
#pragma unroll
        for (int q = 0; q < 4; q++) {
            int ra = lg * 4 + q;
            float u = acc[0][ot][q] * rl0[q];
            u = u > 0.f ? u : __expf(u) - 1.f;
            __builtin_nontemporal_store(u, &out[((size_t)(b * NTOK + i0 + ra)) * FOUT + o]);
            int rb = 16 + lg * 4 + q;
            float v = acc[1][ot][q] * rl1[q];
            v = v > 0.f ? v : __expf(v) - 1.f;
            __builtin_nontemporal_store(v, &out[((size_t)(b * NTOK + i0 + rb)) * FOUT + o]);
        }
    }
}

extern "C" void kernel_launch(void* const* d_in, const int* in_sizes, int n_in,
                              void* d_out, int out_size, void* d_ws, size_t ws_size,
                              hipStream_t stream) {
    const float* x = (const float*)d_in[0];
    const int* adj = (const int*)d_in[1];
    const float* W = (const float*)d_in[2];
    const float* a = (const float*)d_in[3];
    float* out = (float*)d_out;

    char* ws = (char*)d_ws;
    f16* WT = (f16*)ws;                                     // 128 KB
    f16* WhT = (f16*)(ws + 131072);                         // 8 MB swizzled
    float* s1 = (float*)(ws + 131072 + 8388608);            // 64 KB
    float* s2 = s1 + BATCH * NTOK;                          // 64 KB

    k_wt<<<dim3(FOUT / 32, FIN / 32), dim3(32, 32), 0, stream>>>(W, WT);
    k_gemm<<<dim3(BATCH * NTOK / 64), 256, 0, stream>>>(x, WT, a, WhT, s1, s2);
    k_attn<<<dim3(BATCH * NTOK / 32), 512, 0, stream>>>(adj, WhT, s1, s2, out);
}